// Round 6
// baseline (92.408 us; speedup 1.0000x reference)
//
#include <hip/hip_runtime.h>

#define BLK 256
#define QPT 8        // query points per thread (named scalars)
#define SLICES 32    // target slices per direction
#define TT 256       // targets per slice tile (= 8192 / SLICES)
#define CP (TT / 2)  // column pairs per tile

typedef float f32x2 __attribute__((ext_vector_type(2)));

__device__ __forceinline__ f32x2 pk_fma(f32x2 a, f32x2 b, f32x2 c) {
    f32x2 d;
    asm volatile("v_pk_fma_f32 %0, %1, %2, %3" : "=v"(d) : "v"(a), "v"(b), "v"(c));
    return d;
}
__device__ __forceinline__ float min3(float a, float b, float c) {
    float d;
    asm volatile("v_min3_f32 %0, %1, %2, %3" : "=v"(d) : "v"(a), "v"(b), "v"(c));
    return d;
}

#define Q_ITER(F) F(0) F(1) F(2) F(3) F(4) F(5) F(6) F(7)

__global__ __launch_bounds__(256) void init_mins(unsigned int* mins, int n) {
    int i = blockIdx.x * 256 + threadIdx.x;
    if (i < n) mins[i] = 0x7f800000u;  // +inf
}

// dir 0: queries = pred (pc_p), targets = gt  -> P region
// dir 1: queries = gt  (pc_gt), targets = pred -> G region
template <bool USE_ATOMIC>
__global__ __launch_bounds__(BLK) void chamfer_min(
    const float* __restrict__ gt, const float* __restrict__ pp,
    unsigned int* __restrict__ minP, unsigned int* __restrict__ minG,
    float* __restrict__ dP, float* __restrict__ dG,
    int M, int N)
{
    const int dir = (blockIdx.z >= SLICES) ? 1 : 0;
    const int s   = blockIdx.z - dir * SLICES;
    const float* __restrict__ Q = dir ? gt : pp;
    const float* __restrict__ T = dir ? pp : gt;
    const int NQ = dir ? N : M;
    const int NT = dir ? M : N;
    const int b  = blockIdx.y;

    // LDS: column pairs, component-interleaved for packed math:
    //   sT[p][0] = {-2zA,-2zB,-2yA,-2yB}   sT[p][1] = {-2xA,-2xB, wA, wB}
    __shared__ float4 sT[CP][2];
    {
        const float* tb = T + ((size_t)b * NT + (size_t)s * TT) * 3;
        for (int j = threadIdx.x; j < TT; j += BLK) {
            float x = tb[3 * j], y = tb[3 * j + 1], z = tb[3 * j + 2];
            float* base = (float*)&sT[j >> 1][0];
            int h = j & 1;
            base[0 + h] = -2.f * z;
            base[2 + h] = -2.f * y;
            base[4 + h] = -2.f * x;
            base[6 + h] = x * x + y * y + z * z;
        }
    }
    __syncthreads();

    const int q0 = blockIdx.x * (BLK * QPT) + threadIdx.x * QPT;
    if (q0 >= NQ) return;

    // 8 query points = 24 floats = 6 aligned float4 loads -> named scalars
    const float4* qv = (const float4*)(Q + ((size_t)b * NQ + q0) * 3);
    float4 f0 = qv[0], f1 = qv[1], f2 = qv[2], f3 = qv[3], f4 = qv[4], f5 = qv[5];

#define DECLQ(i) float qx##i, qy##i, qz##i, bb##i = 3.0e38f;
    Q_ITER(DECLQ)
#undef DECLQ
    qx0 = f0.x; qy0 = f0.y; qz0 = f0.z;
    qx1 = f0.w; qy1 = f1.x; qz1 = f1.y;
    qx2 = f1.z; qy2 = f1.w; qz2 = f2.x;
    qx3 = f2.y; qy3 = f2.z; qz3 = f2.w;
    qx4 = f3.x; qy4 = f3.y; qz4 = f3.z;
    qx5 = f3.w; qy5 = f4.x; qz5 = f4.y;
    qx6 = f4.z; qy6 = f4.w; qz6 = f5.x;
    qx7 = f5.y; qy7 = f5.z; qz7 = f5.w;

    // duplicate each query scalar into both packed halves (one-time cost)
#define DUPQ(i) f32x2 px##i = {qx##i, qx##i}, py##i = {qy##i, qy##i}, pz##i = {qz##i, qz##i};
    Q_ITER(DUPQ)
#undef DUPQ

    // min over column pairs of (|t|^2 - 2 q.t), packed 2 columns per inst:
    // AB = pk_fma(pz,Sz,Sw); pk_fma(py,Sy,AB); pk_fma(px,Sx,AB); bb=min3(bb,AB.x,AB.y)
    for (int p = 0; p < CP; ++p) {
        float4 v0 = sT[p][0];
        float4 v1 = sT[p][1];
        f32x2 Sz = {v0.x, v0.y};
        f32x2 Sy = {v0.z, v0.w};
        f32x2 Sx = {v1.x, v1.y};
        f32x2 Sw = {v1.z, v1.w};
#define STEP(i) { \
        f32x2 AB = pk_fma(pz##i, Sz, Sw); \
        AB = pk_fma(py##i, Sy, AB); \
        AB = pk_fma(px##i, Sx, AB); \
        bb##i = min3(bb##i, AB.x, AB.y); }
        Q_ITER(STEP)
#undef STEP
    }

    unsigned int* mp = (dir ? minG : minP) + (size_t)b * NQ + q0;
    float* op = (dir ? dG : dP) + (size_t)s * ((size_t)gridDim.y * NQ)
                                + (size_t)b * NQ + q0;
#define FIN(i) { \
        float aq = __builtin_fmaf(qx##i, qx##i, \
                   __builtin_fmaf(qy##i, qy##i, qz##i * qz##i)); \
        float d = fmaxf(bb##i + aq, 0.f); \
        if (USE_ATOMIC) atomicMin(&mp[i], __float_as_uint(d)); \
        else op[i] = d; }
    Q_ITER(FIN)
#undef FIN
}

__device__ double block_reduce_d(double v) {
    __shared__ double red[4];
    for (int o = 32; o > 0; o >>= 1) v += __shfl_down(v, o);
    int lane = threadIdx.x & 63, w = threadIdx.x >> 6;
    if (lane == 0) red[w] = v;
    __syncthreads();
    if (threadIdx.x == 0) v = red[0] + red[1] + red[2] + red[3];
    return v;
}

// fold SLICES per-slice mins + weighted sum
__global__ __launch_bounds__(256) void reduce1_slices(
    const float* __restrict__ dP, const float* __restrict__ dG,
    double* __restrict__ partials, int EM, int EN, double wP, double wG) {
    const int E = EM + EN;
    double acc = 0.0;
    for (int i = blockIdx.x * 256 + threadIdx.x; i < E; i += 256 * 256) {
        const float* base; int stride; double w;
        if (i < EM) { base = dP + i;        stride = EM; w = wP; }
        else        { base = dG + (i - EM); stride = EN; w = wG; }
        float m = base[0];
#pragma unroll
        for (int s = 1; s < SLICES; ++s) m = fminf(m, base[(size_t)s * stride]);
        acc += (double)m * w;
    }
    double s = block_reduce_d(acc);
    if (threadIdx.x == 0) partials[blockIdx.x] = s;
}

__global__ __launch_bounds__(256) void reduce1_atomic(
    const unsigned int* __restrict__ mins, double* __restrict__ partials,
    int EM, int E, double wP, double wG) {
    double acc = 0.0;
    for (int i = blockIdx.x * 256 + threadIdx.x; i < E; i += 256 * 256)
        acc += (double)__uint_as_float(mins[i]) * (i < EM ? wP : wG);
    double s = block_reduce_d(acc);
    if (threadIdx.x == 0) partials[blockIdx.x] = s;
}

__global__ __launch_bounds__(256) void reduce2(const double* __restrict__ partials,
                                               float* __restrict__ out) {
    double s = block_reduce_d(partials[threadIdx.x]);
    if (threadIdx.x == 0) out[0] = (float)s;
}

extern "C" void kernel_launch(void* const* d_in, const int* in_sizes, int n_in,
                              void* d_out, int out_size, void* d_ws, size_t ws_size,
                              hipStream_t stream) {
    const float* gt = (const float*)d_in[0];  // pc_gt (B,N,3)
    const float* pp = (const float*)d_in[1];  // pc_p  (B,M,3)
    const int B = 8;
    const int N = in_sizes[0] / (B * 3);
    const int M = in_sizes[1] / (B * 3);
    const int EM = B * M, EN = B * N, E = EM + EN;
    float* out = (float*)d_out;

    const int NQmax = (M > N) ? M : N;
    dim3 grid((NQmax + BLK * QPT - 1) / (BLK * QPT), B, 2 * SLICES);

    const size_t needNA = (size_t)SLICES * E * 4 + 256 * 8;
    if (ws_size >= needNA) {
        // no-atomic path: per-slice buffers + fused slice-min reduction
        float* dP = (float*)d_ws;                       // SLICES x EM
        float* dG = dP + (size_t)SLICES * EM;           // SLICES x EN
        double* partials = (double*)((char*)d_ws + (size_t)SLICES * E * 4);
        chamfer_min<false><<<grid, BLK, 0, stream>>>(gt, pp, nullptr, nullptr,
                                                     dP, dG, M, N);
        reduce1_slices<<<256, 256, 0, stream>>>(dP, dG, partials, EM, EN,
                                                1.0 / (double)EM, 1.0 / (double)EN);
        reduce2<<<1, 256, 0, stream>>>(partials, out);
    } else {
        // fallback: atomic-min path
        unsigned int* mins = (unsigned int*)d_ws;
        double* partials = (double*)((char*)d_ws + (size_t)E * 4);
        init_mins<<<(E + 255) / 256, 256, 0, stream>>>(mins, E);
        chamfer_min<true><<<grid, BLK, 0, stream>>>(gt, pp, mins, mins + EM,
                                                    nullptr, nullptr, M, N);
        reduce1_atomic<<<256, 256, 0, stream>>>(mins, partials, EM, E,
                                                1.0 / (double)EM, 1.0 / (double)EN);
        reduce2<<<1, 256, 0, stream>>>(partials, out);
    }
}

// Round 7
// 86.849 us; speedup vs baseline: 1.0640x; 1.0640x over previous
//
#include <hip/hip_runtime.h>

#define BLK 256
#define QPT 8        // query points per thread (named scalars)
#define SLICES 32    // target slices per direction
#define TT 256       // targets per slice tile (= 8192 / SLICES)
#define CP (TT / 2)  // column pairs per tile

typedef float f32x2 __attribute__((ext_vector_type(2)));

#define Q_ITER(F) F(0) F(1) F(2) F(3) F(4) F(5) F(6) F(7)

__global__ __launch_bounds__(256) void init_mins(unsigned int* mins, int n) {
    int i = blockIdx.x * 256 + threadIdx.x;
    if (i < n) mins[i] = 0x7f800000u;  // +inf
}

// dir 0: queries = pred (pc_p), targets = gt  -> P region
// dir 1: queries = gt  (pc_gt), targets = pred -> G region
template <bool USE_ATOMIC>
__global__ __launch_bounds__(BLK) void chamfer_min(
    const float* __restrict__ gt, const float* __restrict__ pp,
    unsigned int* __restrict__ minP, unsigned int* __restrict__ minG,
    float* __restrict__ dP, float* __restrict__ dG,
    int M, int N)
{
    const int dir = (blockIdx.z >= SLICES) ? 1 : 0;
    const int s   = blockIdx.z - dir * SLICES;
    const float* __restrict__ Q = dir ? gt : pp;
    const float* __restrict__ T = dir ? pp : gt;
    const int NQ = dir ? N : M;
    const int NT = dir ? M : N;
    const int b  = blockIdx.y;

    // LDS: column pairs, component-interleaved for packed math:
    //   sT[p][0] = {-2zA,-2zB,-2yA,-2yB}   sT[p][1] = {-2xA,-2xB, wA, wB}
    __shared__ float4 sT[CP][2];
    {
        const float* tb = T + ((size_t)b * NT + (size_t)s * TT) * 3;
        for (int j = threadIdx.x; j < TT; j += BLK) {
            float x = tb[3 * j], y = tb[3 * j + 1], z = tb[3 * j + 2];
            float* base = (float*)&sT[j >> 1][0];
            int h = j & 1;
            base[0 + h] = -2.f * z;
            base[2 + h] = -2.f * y;
            base[4 + h] = -2.f * x;
            base[6 + h] = x * x + y * y + z * z;
        }
    }
    __syncthreads();

    const int q0 = blockIdx.x * (BLK * QPT) + threadIdx.x * QPT;
    if (q0 >= NQ) return;

    // 8 query points = 24 floats = 6 aligned float4 loads -> named scalars
    const float4* qv = (const float4*)(Q + ((size_t)b * NQ + q0) * 3);
    float4 f0 = qv[0], f1 = qv[1], f2 = qv[2], f3 = qv[3], f4 = qv[4], f5 = qv[5];

#define DECLQ(i) float qx##i, qy##i, qz##i, bb##i = 3.0e38f;
    Q_ITER(DECLQ)
#undef DECLQ
    qx0 = f0.x; qy0 = f0.y; qz0 = f0.z;
    qx1 = f0.w; qy1 = f1.x; qz1 = f1.y;
    qx2 = f1.z; qy2 = f1.w; qz2 = f2.x;
    qx3 = f2.y; qy3 = f2.z; qz3 = f2.w;
    qx4 = f3.x; qy4 = f3.y; qz4 = f3.z;
    qx5 = f3.w; qy5 = f4.x; qz5 = f4.y;
    qx6 = f4.z; qy6 = f4.w; qz6 = f5.x;
    qx7 = f5.y; qy7 = f5.z; qz7 = f5.w;

    // duplicate each query scalar into both packed halves (one-time; the
    // backend can fold splats into VOP3P op_sel)
#define DUPQ(i) f32x2 px##i = {qx##i, qx##i}, py##i = {qy##i, qy##i}, pz##i = {qz##i, qz##i};
    Q_ITER(DUPQ)
#undef DUPQ

    // min over column pairs of (|t|^2 - 2 q.t), packed 2 columns per inst:
    // AB = pk_fma(pz,Sz,Sw); pk_fma(py,Sy,AB); pk_fma(px,Sx,AB);
    // bb = min3(bb, AB.x, AB.y)   [fminf chain fuses to v_min3_f32]
    for (int p = 0; p < CP; ++p) {
        float4 v0 = sT[p][0];
        float4 v1 = sT[p][1];
        f32x2 Sz = {v0.x, v0.y};
        f32x2 Sy = {v0.z, v0.w};
        f32x2 Sx = {v1.x, v1.y};
        f32x2 Sw = {v1.z, v1.w};
#define STEP(i) { \
        f32x2 AB = __builtin_elementwise_fma(pz##i, Sz, Sw); \
        AB = __builtin_elementwise_fma(py##i, Sy, AB); \
        AB = __builtin_elementwise_fma(px##i, Sx, AB); \
        bb##i = fminf(fminf(bb##i, AB.x), AB.y); }
        Q_ITER(STEP)
#undef STEP
    }

    unsigned int* mp = (dir ? minG : minP) + (size_t)b * NQ + q0;
    float* op = (dir ? dG : dP) + (size_t)s * ((size_t)gridDim.y * NQ)
                                + (size_t)b * NQ + q0;
#define FIN(i) { \
        float aq = __builtin_fmaf(qx##i, qx##i, \
                   __builtin_fmaf(qy##i, qy##i, qz##i * qz##i)); \
        float d = fmaxf(bb##i + aq, 0.f); \
        if (USE_ATOMIC) atomicMin(&mp[i], __float_as_uint(d)); \
        else op[i] = d; }
    Q_ITER(FIN)
#undef FIN
}

__device__ double block_reduce_d(double v) {
    __shared__ double red[4];
    for (int o = 32; o > 0; o >>= 1) v += __shfl_down(v, o);
    int lane = threadIdx.x & 63, w = threadIdx.x >> 6;
    if (lane == 0) red[w] = v;
    __syncthreads();
    if (threadIdx.x == 0) v = red[0] + red[1] + red[2] + red[3];
    return v;
}

// fold SLICES per-slice mins + weighted sum
__global__ __launch_bounds__(256) void reduce1_slices(
    const float* __restrict__ dP, const float* __restrict__ dG,
    double* __restrict__ partials, int EM, int EN, double wP, double wG) {
    const int E = EM + EN;
    double acc = 0.0;
    for (int i = blockIdx.x * 256 + threadIdx.x; i < E; i += 256 * 256) {
        const float* base; int stride; double w;
        if (i < EM) { base = dP + i;        stride = EM; w = wP; }
        else        { base = dG + (i - EM); stride = EN; w = wG; }
        float m = base[0];
#pragma unroll
        for (int s = 1; s < SLICES; ++s) m = fminf(m, base[(size_t)s * stride]);
        acc += (double)m * w;
    }
    double s = block_reduce_d(acc);
    if (threadIdx.x == 0) partials[blockIdx.x] = s;
}

__global__ __launch_bounds__(256) void reduce1_atomic(
    const unsigned int* __restrict__ mins, double* __restrict__ partials,
    int EM, int E, double wP, double wG) {
    double acc = 0.0;
    for (int i = blockIdx.x * 256 + threadIdx.x; i < E; i += 256 * 256)
        acc += (double)__uint_as_float(mins[i]) * (i < EM ? wP : wG);
    double s = block_reduce_d(acc);
    if (threadIdx.x == 0) partials[blockIdx.x] = s;
}

__global__ __launch_bounds__(256) void reduce2(const double* __restrict__ partials,
                                               float* __restrict__ out) {
    double s = block_reduce_d(partials[threadIdx.x]);
    if (threadIdx.x == 0) out[0] = (float)s;
}

extern "C" void kernel_launch(void* const* d_in, const int* in_sizes, int n_in,
                              void* d_out, int out_size, void* d_ws, size_t ws_size,
                              hipStream_t stream) {
    const float* gt = (const float*)d_in[0];  // pc_gt (B,N,3)
    const float* pp = (const float*)d_in[1];  // pc_p  (B,M,3)
    const int B = 8;
    const int N = in_sizes[0] / (B * 3);
    const int M = in_sizes[1] / (B * 3);
    const int EM = B * M, EN = B * N, E = EM + EN;
    float* out = (float*)d_out;

    const int NQmax = (M > N) ? M : N;
    dim3 grid((NQmax + BLK * QPT - 1) / (BLK * QPT), B, 2 * SLICES);

    const size_t needNA = (size_t)SLICES * E * 4 + 256 * 8;
    if (ws_size >= needNA) {
        // no-atomic path: per-slice buffers + fused slice-min reduction
        float* dP = (float*)d_ws;                       // SLICES x EM
        float* dG = dP + (size_t)SLICES * EM;           // SLICES x EN
        double* partials = (double*)((char*)d_ws + (size_t)SLICES * E * 4);
        chamfer_min<false><<<grid, BLK, 0, stream>>>(gt, pp, nullptr, nullptr,
                                                     dP, dG, M, N);
        reduce1_slices<<<256, 256, 0, stream>>>(dP, dG, partials, EM, EN,
                                                1.0 / (double)EM, 1.0 / (double)EN);
        reduce2<<<1, 256, 0, stream>>>(partials, out);
    } else {
        // fallback: atomic-min path
        unsigned int* mins = (unsigned int*)d_ws;
        double* partials = (double*)((char*)d_ws + (size_t)E * 4);
        init_mins<<<(E + 255) / 256, 256, 0, stream>>>(mins, E);
        chamfer_min<true><<<grid, BLK, 0, stream>>>(gt, pp, mins, mins + EM,
                                                    nullptr, nullptr, M, N);
        reduce1_atomic<<<256, 256, 0, stream>>>(mins, partials, EM, E,
                                                1.0 / (double)EM, 1.0 / (double)EN);
        reduce2<<<1, 256, 0, stream>>>(partials, out);
    }
}